// Round 3
// baseline (500.348 us; speedup 1.0000x reference)
//
#include <hip/hip_runtime.h>

typedef unsigned int u32;
typedef unsigned short u16;
typedef __attribute__((ext_vector_type(8))) __bf16 bf16x8;
typedef __attribute__((ext_vector_type(4))) float f32x4;

#define AS1 __attribute__((address_space(1)))
#define AS3 __attribute__((address_space(3)))

__device__ __forceinline__ void gl_lds16(const void* g, void* l) {
  __builtin_amdgcn_global_load_lds((const AS1 void*)g, (AS3 void*)l, 16, 0, 0);
}

__device__ __forceinline__ u16 f2bf(float f) {
  union { float f; u32 u; } v; v.f = f;
  u32 r = v.u + 0x7fffu + ((v.u >> 16) & 1u);
  return (u16)(r >> 16);
}

__device__ __forceinline__ u32 cvt_pk_bf16(float a, float b) {
  u32 r;
  asm("v_cvt_pk_bf16_f32 %0, %1, %2" : "=v"(r) : "v"(a), "v"(b));
  return r;
}

// ---------------- f32 -> bf16 conversion (3 arrays per launch) ----------------
__global__ void cvt3_kernel(const float* __restrict__ a, const float* __restrict__ b,
                            const float* __restrict__ c, u16* __restrict__ oa,
                            u16* __restrict__ ob, u16* __restrict__ oc, int n4) {
  const float* in = (blockIdx.y == 0) ? a : (blockIdx.y == 1) ? b : c;
  u16* out = (blockIdx.y == 0) ? oa : (blockIdx.y == 1) ? ob : oc;
  int i = blockIdx.x * blockDim.x + threadIdx.x;
  if (i >= n4) return;
  float4 v = ((const float4*)in)[i];
  ushort4 o;
  o.x = f2bf(v.x); o.y = f2bf(v.y); o.z = f2bf(v.z); o.w = f2bf(v.w);
  ((ushort4*)out)[i] = o;
}

// ---------------- projection GEMM: C[m,n] = sum_k X[m,k] W[n,k] ----------------
// M=4096, N=1024, K=1024. 128x128 tile, BK=32, 4 waves, 2-phase prefetch dbuf.
// which==0 -> Q [b,h,s,d]; which==1 -> K [b,h,s,d]; which==2 -> V^T [b,h,d,s]
__global__ void __launch_bounds__(256) proj_gemm(
    const u16* __restrict__ Xq, const u16* __restrict__ Xk, const u16* __restrict__ Xv,
    const u16* __restrict__ Wq, const u16* __restrict__ Wk, const u16* __restrict__ Wv,
    u16* __restrict__ Qo, u16* __restrict__ Ko, u16* __restrict__ Vto)
{
  const int which = blockIdx.z;
  const u16* X = (which == 0) ? Xq : (which == 1) ? Xk : Xv;
  const u16* W = (which == 0) ? Wq : (which == 1) ? Wk : Wv;

  __shared__ u16 As[2][128 * 32];
  __shared__ u16 Bs[2][128 * 32];

  const int t = threadIdx.x;
  const int lane = t & 63;
  const int w = t >> 6;
  const int wr = w >> 1, wc = w & 1;
  const int lr = lane & 15, lg = lane >> 4;
  const int m0 = blockIdx.y * 128, n0 = blockIdx.x * 128;

  const int e0 = t * 8, e1 = t * 8 + 2048;
  const int r0 = e0 >> 5, c0 = e0 & 31, r1 = e1 >> 5, c1 = e1 & 31;

  const f32x4 ZERO = {0.f, 0.f, 0.f, 0.f};
  f32x4 acc[4][4];
  for (int i = 0; i < 4; ++i)
    for (int j = 0; j < 4; ++j) acc[i][j] = ZERO;

  gl_lds16(&X[(size_t)(m0 + r0) * 1024 + c0], &As[0][e0]);
  gl_lds16(&X[(size_t)(m0 + r1) * 1024 + c1], &As[0][e1]);
  gl_lds16(&W[(size_t)(n0 + r0) * 1024 + c0], &Bs[0][e0]);
  gl_lds16(&W[(size_t)(n0 + r1) * 1024 + c1], &Bs[0][e1]);

  for (int ks = 0; ks < 32; ++ks) {
    __syncthreads();
    if (ks + 1 < 32) {
      int kn = (ks + 1) * 32;
      int nb = (ks + 1) & 1;
      gl_lds16(&X[(size_t)(m0 + r0) * 1024 + kn + c0], &As[nb][e0]);
      gl_lds16(&X[(size_t)(m0 + r1) * 1024 + kn + c1], &As[nb][e1]);
      gl_lds16(&W[(size_t)(n0 + r0) * 1024 + kn + c0], &Bs[nb][e0]);
      gl_lds16(&W[(size_t)(n0 + r1) * 1024 + kn + c1], &Bs[nb][e1]);
    }
    const u16* Ab = &As[ks & 1][0];
    const u16* Bb = &Bs[ks & 1][0];
    bf16x8 a[4], b[4];
#pragma unroll
    for (int i = 0; i < 4; ++i)
      a[i] = *(const bf16x8*)&Ab[(wr * 64 + i * 16 + lr) * 32 + lg * 8];
#pragma unroll
    for (int j = 0; j < 4; ++j)
      b[j] = *(const bf16x8*)&Bb[(wc * 64 + j * 16 + lr) * 32 + lg * 8];
#pragma unroll
    for (int i = 0; i < 4; ++i)
#pragma unroll
      for (int j = 0; j < 4; ++j)
        acc[i][j] = __builtin_amdgcn_mfma_f32_16x16x32_bf16(a[i], b[j], acc[i][j], 0, 0, 0);
  }

#pragma unroll
  for (int i = 0; i < 4; ++i) {
#pragma unroll
    for (int j = 0; j < 4; ++j) {
#pragma unroll
      for (int r = 0; r < 4; ++r) {
        int m = m0 + wr * 64 + i * 16 + lg * 4 + r;
        int n = n0 + wc * 64 + j * 16 + lr;
        u16 bfv = f2bf(acc[i][j][r]);
        int bb = m >> 11, s = m & 2047, h = n >> 6, d = n & 63;
        if (which < 2) {
          u16* O = (which == 0) ? Qo : Ko;
          O[((size_t)(bb * 16 + h) * 2048 + s) * 64 + d] = bfv;
        } else {
          Vto[((size_t)(bb * 16 + h) * 64 + d) * 2048 + s] = bfv;
        }
      }
    }
  }
}

// ---------------- attention pass 1: softmax denom l per row ----------------
// Barrier-free: K read global->VGPR (L2-resident). Swapped mfma(K,Q):
// lane holds S[q=lr][k=jj*16+lg*4+r]. No-max softmax (clamp 30).
__global__ void __launch_bounds__(256) attn_l(
    const u16* __restrict__ Qw, const u16* __restrict__ Kw, float* __restrict__ ml)
{
  const int t = threadIdx.x, lane = t & 63, w = t >> 6;
  const int lr = lane & 15, lg = lane >> 4;
  const int q0 = blockIdx.x * 64, bh = blockIdx.y;
  const u16* Qbase = Qw + (size_t)bh * 2048 * 64;
  const u16* Kbase = Kw + (size_t)bh * 2048 * 64;

  const int qrow = q0 + w * 16 + lr;
  bf16x8 qa[2];
#pragma unroll
  for (int sl = 0; sl < 2; ++sl)
    qa[sl] = *(const bf16x8*)&Qbase[(size_t)qrow * 64 + sl * 32 + lg * 8];

  const f32x4 ZERO = {0.f, 0.f, 0.f, 0.f};
  float lacc = 0.f;

  for (int kt = 0; kt < 2048; kt += 64) {
    f32x4 sacc[4];
#pragma unroll
    for (int jj = 0; jj < 4; ++jj) sacc[jj] = ZERO;
    bf16x8 kb[2][4];
#pragma unroll
    for (int sl = 0; sl < 2; ++sl)
#pragma unroll
      for (int jj = 0; jj < 4; ++jj)
        kb[sl][jj] = *(const bf16x8*)&Kbase[(size_t)(kt + jj * 16 + lr) * 64 + sl * 32 + lg * 8];
#pragma unroll
    for (int sl = 0; sl < 2; ++sl)
#pragma unroll
      for (int jj = 0; jj < 4; ++jj)
        sacc[jj] = __builtin_amdgcn_mfma_f32_16x16x32_bf16(kb[sl][jj], qa[sl], sacc[jj], 0, 0, 0);
#pragma unroll
    for (int jj = 0; jj < 4; ++jj)
#pragma unroll
      for (int r = 0; r < 4; ++r)
        lacc += __expf(fminf(sacc[jj][r] * 0.125f, 30.f));
  }
  lacc += __shfl_xor(lacc, 16);
  lacc += __shfl_xor(lacc, 32);
  if (lg == 0) ml[(size_t)bh * 2048 + qrow] = lacc;
}

// ---------------- attention pass 2: attn write + PV -> ctx ----------------
// Barrier-free; per-wave private P in LDS (ds-pipe in-order, no syncthreads).
__global__ void __launch_bounds__(256) attn_av(
    const u16* __restrict__ Qw, const u16* __restrict__ Kw, const u16* __restrict__ VTw,
    const float* __restrict__ ml, float* __restrict__ attn_out, float* __restrict__ ctx)
{
  __shared__ u16 Ps[4][16 * 72];   // per-wave P rows: q=lr, 64 k, stride 72 u16

  const int t = threadIdx.x, lane = t & 63, w = t >> 6;
  const int lr = lane & 15, lg = lane >> 4;
  const int q0 = blockIdx.x * 64, bh = blockIdx.y;
  const u16* Qbase = Qw + (size_t)bh * 2048 * 64;
  const u16* Kbase = Kw + (size_t)bh * 2048 * 64;
  const u16* VTbase = VTw + (size_t)bh * 64 * 2048;

  const int qrow = q0 + w * 16 + lr;
  bf16x8 qa[2];
#pragma unroll
  for (int sl = 0; sl < 2; ++sl)
    qa[sl] = *(const bf16x8*)&Qbase[(size_t)qrow * 64 + sl * 32 + lg * 8];

  const float linv = 1.f / ml[(size_t)bh * 2048 + qrow];
  float linv2[4];
#pragma unroll
  for (int r = 0; r < 4; ++r)
    linv2[r] = 1.f / ml[(size_t)bh * 2048 + q0 + w * 16 + lg * 4 + r];

  const f32x4 ZERO = {0.f, 0.f, 0.f, 0.f};
  f32x4 acc_o[4];
#pragma unroll
  for (int j = 0; j < 4; ++j) acc_o[j] = ZERO;

  float* arow = attn_out + ((size_t)bh * 2048 + qrow) * 2048;
  u16* Pw = &Ps[w][0];

  for (int kt = 0; kt < 2048; kt += 64) {
    // S^T tile: lane holds S[q=lr][k=kt+jj*16+lg*4+r]
    f32x4 sacc[4];
#pragma unroll
    for (int jj = 0; jj < 4; ++jj) sacc[jj] = ZERO;
    bf16x8 kb[2][4];
#pragma unroll
    for (int sl = 0; sl < 2; ++sl)
#pragma unroll
      for (int jj = 0; jj < 4; ++jj)
        kb[sl][jj] = *(const bf16x8*)&Kbase[(size_t)(kt + jj * 16 + lr) * 64 + sl * 32 + lg * 8];
#pragma unroll
    for (int sl = 0; sl < 2; ++sl)
#pragma unroll
      for (int jj = 0; jj < 4; ++jj)
        sacc[jj] = __builtin_amdgcn_mfma_f32_16x16x32_bf16(kb[sl][jj], qa[sl], sacc[jj], 0, 0, 0);

    // exp, vectorized attn store (float4/lane), P -> per-wave LDS (8B/lane/jj)
#pragma unroll
    for (int jj = 0; jj < 4; ++jj) {
      f32x4 e;
#pragma unroll
      for (int r = 0; r < 4; ++r)
        e[r] = __expf(fminf(sacc[jj][r] * 0.125f, 30.f));
      f32x4 st = e * linv;
      *(f32x4*)&arow[kt + jj * 16 + lg * 4] = st;
      u32 p01 = cvt_pk_bf16(e[0], e[1]);
      u32 p23 = cvt_pk_bf16(e[2], e[3]);
      *(uint2*)&Pw[lr * 72 + jj * 16 + lg * 4] = make_uint2(p01, p23);
    }
    asm volatile("s_waitcnt lgkmcnt(0)" ::: "memory");
    __builtin_amdgcn_sched_barrier(0);

    bf16x8 pa[2];
#pragma unroll
    for (int sl = 0; sl < 2; ++sl)
      pa[sl] = *(const bf16x8*)&Pw[lr * 72 + sl * 32 + lg * 8];
#pragma unroll
    for (int jj = 0; jj < 4; ++jj) {
#pragma unroll
      for (int sl = 0; sl < 2; ++sl) {
        bf16x8 vb = *(const bf16x8*)&VTbase[(size_t)(jj * 16 + lr) * 2048 + kt + sl * 32 + lg * 8];
        acc_o[jj] = __builtin_amdgcn_mfma_f32_16x16x32_bf16(pa[sl], vb, acc_o[jj], 0, 0, 0);
      }
    }
  }

  const int bb = bh >> 4, h = bh & 15;
#pragma unroll
  for (int jj = 0; jj < 4; ++jj) {
#pragma unroll
    for (int r = 0; r < 4; ++r) {
      int srow = q0 + w * 16 + lg * 4 + r;
      ctx[((size_t)bb * 2048 + srow) * 1024 + h * 64 + jj * 16 + lr] = acc_o[jj][r] * linv2[r];
    }
  }
}

// ---------------- residual + LayerNorm ----------------
__global__ void __launch_bounds__(256) ln_kernel(
    const float* __restrict__ ctx, const float* __restrict__ res, float* __restrict__ out)
{
  __shared__ float red[8];
  int row = blockIdx.x;
  int t = threadIdx.x;
  int lane = t & 63, w = t >> 6;
  size_t base = (size_t)row * 1024 + t * 4;
  float4 c = *(const float4*)&ctx[base];
  float4 rs = *(const float4*)&res[base];
  float x0 = c.x + rs.x, x1 = c.y + rs.y, x2 = c.z + rs.z, x3 = c.w + rs.w;
  float s = x0 + x1 + x2 + x3;
  float q = x0 * x0 + x1 * x1 + x2 * x2 + x3 * x3;
#pragma unroll
  for (int off = 1; off < 64; off <<= 1) {
    s += __shfl_xor(s, off);
    q += __shfl_xor(q, off);
  }
  if (lane == 0) { red[w] = s; red[w + 4] = q; }
  __syncthreads();
  s = red[0] + red[1] + red[2] + red[3];
  q = red[4] + red[5] + red[6] + red[7];
  float mu = s * (1.f / 1024.f);
  float var = q * (1.f / 1024.f) - mu * mu;
  float inv = rsqrtf(var + 1e-5f);
  float4 o;
  o.x = (x0 - mu) * inv; o.y = (x1 - mu) * inv; o.z = (x2 - mu) * inv; o.w = (x3 - mu) * inv;
  *(float4*)&out[base] = o;
}

extern "C" void kernel_launch(void* const* d_in, const int* in_sizes, int n_in,
                              void* d_out, int out_size, void* d_ws, size_t ws_size,
                              hipStream_t stream) {
  (void)in_sizes; (void)n_in; (void)out_size; (void)ws_size;
  const float* inQ = (const float*)d_in[0];
  const float* inK = (const float*)d_in[1];
  const float* inV = (const float*)d_in[2];
  const float* wQ  = (const float*)d_in[3];
  const float* wK  = (const float*)d_in[4];
  const float* wV  = (const float*)d_in[5];

  char* ws = (char*)d_ws;
  const size_t NELEM = 4096u * 1024u;
  u16* Qbf  = (u16*)(ws);                        // 8MB  [b,h,s,d] bf16
  u16* Kbf  = (u16*)(ws + (8ull << 20));         // 8MB
  u16* VTbf = (u16*)(ws + (16ull << 20));        // 8MB  [b,h,d,s] bf16
  u16* Xq   = (u16*)(ws + (24ull << 20));
  u16* Xk   = (u16*)(ws + (32ull << 20));
  u16* Xv   = (u16*)(ws + (40ull << 20));
  u16* Wqb  = (u16*)(ws + (48ull << 20));
  u16* Wkb  = (u16*)(ws + (50ull << 20));
  u16* Wvb  = (u16*)(ws + (52ull << 20));
  float* ml  = (float*)(ws + (54ull << 20));     // 256KB (l per row)
  float* ctx = (float*)(ws + (56ull << 20));     // 16MB f32 [b,s,1024]

  float* out  = (float*)d_out;
  float* attn = out + NELEM;

  dim3 b256(256);
  cvt3_kernel<<<dim3(4096, 3), b256, 0, stream>>>(inQ, inK, inV, Xq, Xk, Xv, (int)(NELEM / 4));
  cvt3_kernel<<<dim3(1024, 3), b256, 0, stream>>>(wQ, wK, wV, Wqb, Wkb, Wvb, 1048576 / 4);

  proj_gemm<<<dim3(8, 32, 3), b256, 0, stream>>>(Xq, Xk, Xv, Wqb, Wkb, Wvb, Qbf, Kbf, VTbf);

  attn_l<<<dim3(32, 32), b256, 0, stream>>>(Qbf, Kbf, ml);
  attn_av<<<dim3(32, 32), b256, 0, stream>>>(Qbf, Kbf, VTbf, ml, attn, ctx);

  ln_kernel<<<dim3(4096), b256, 0, stream>>>(ctx, inQ, out);
}

// Round 4
// 316.915 us; speedup vs baseline: 1.5788x; 1.5788x over previous
//
#include <hip/hip_runtime.h>

typedef unsigned int u32;
typedef unsigned short u16;
typedef __attribute__((ext_vector_type(8))) __bf16 bf16x8;
typedef __attribute__((ext_vector_type(4))) float f32x4;

#define AS1 __attribute__((address_space(1)))
#define AS3 __attribute__((address_space(3)))

__device__ __forceinline__ void gl_lds16(const void* g, void* l) {
  __builtin_amdgcn_global_load_lds((const AS1 void*)g, (AS3 void*)l, 16, 0, 0);
}

__device__ __forceinline__ u16 f2bf(float f) {
  union { float f; u32 u; } v; v.f = f;
  u32 r = v.u + 0x7fffu + ((v.u >> 16) & 1u);
  return (u16)(r >> 16);
}

__device__ __forceinline__ u32 cvt_pk_bf16(float a, float b) {
  u32 r;
  asm("v_cvt_pk_bf16_f32 %0, %1, %2" : "=v"(r) : "v"(a), "v"(b));
  return r;
}

// ---------------- f32 -> bf16 conversion (3 arrays per launch) ----------------
__global__ void cvt3_kernel(const float* __restrict__ a, const float* __restrict__ b,
                            const float* __restrict__ c, u16* __restrict__ oa,
                            u16* __restrict__ ob, u16* __restrict__ oc, int n4) {
  const float* in = (blockIdx.y == 0) ? a : (blockIdx.y == 1) ? b : c;
  u16* out = (blockIdx.y == 0) ? oa : (blockIdx.y == 1) ? ob : oc;
  int i = blockIdx.x * blockDim.x + threadIdx.x;
  if (i >= n4) return;
  float4 v = ((const float4*)in)[i];
  ushort4 o;
  o.x = f2bf(v.x); o.y = f2bf(v.y); o.z = f2bf(v.z); o.w = f2bf(v.w);
  ((ushort4*)out)[i] = o;
}

// ---------------- projection GEMM: C[m,n] = sum_k X[m,k] W[n,k] ----------------
// 128x128 tile, BK=32, 4 waves, 2-phase prefetch dbuf (R2-proven).
__global__ void __launch_bounds__(256) proj_gemm(
    const u16* __restrict__ Xq, const u16* __restrict__ Xk, const u16* __restrict__ Xv,
    const u16* __restrict__ Wq, const u16* __restrict__ Wk, const u16* __restrict__ Wv,
    u16* __restrict__ Qo, u16* __restrict__ Ko, u16* __restrict__ Vto)
{
  const int which = blockIdx.z;
  const u16* X = (which == 0) ? Xq : (which == 1) ? Xk : Xv;
  const u16* W = (which == 0) ? Wq : (which == 1) ? Wk : Wv;

  __shared__ u16 As[2][128 * 32];
  __shared__ u16 Bs[2][128 * 32];

  const int t = threadIdx.x;
  const int lane = t & 63;
  const int w = t >> 6;
  const int wr = w >> 1, wc = w & 1;
  const int lr = lane & 15, lg = lane >> 4;
  const int m0 = blockIdx.y * 128, n0 = blockIdx.x * 128;

  const int e0 = t * 8, e1 = t * 8 + 2048;
  const int r0 = e0 >> 5, c0 = e0 & 31, r1 = e1 >> 5, c1 = e1 & 31;

  const f32x4 ZERO = {0.f, 0.f, 0.f, 0.f};
  f32x4 acc[4][4];
  for (int i = 0; i < 4; ++i)
    for (int j = 0; j < 4; ++j) acc[i][j] = ZERO;

  gl_lds16(&X[(size_t)(m0 + r0) * 1024 + c0], &As[0][e0]);
  gl_lds16(&X[(size_t)(m0 + r1) * 1024 + c1], &As[0][e1]);
  gl_lds16(&W[(size_t)(n0 + r0) * 1024 + c0], &Bs[0][e0]);
  gl_lds16(&W[(size_t)(n0 + r1) * 1024 + c1], &Bs[0][e1]);

  for (int ks = 0; ks < 32; ++ks) {
    __syncthreads();
    if (ks + 1 < 32) {
      int kn = (ks + 1) * 32;
      int nb = (ks + 1) & 1;
      gl_lds16(&X[(size_t)(m0 + r0) * 1024 + kn + c0], &As[nb][e0]);
      gl_lds16(&X[(size_t)(m0 + r1) * 1024 + kn + c1], &As[nb][e1]);
      gl_lds16(&W[(size_t)(n0 + r0) * 1024 + kn + c0], &Bs[nb][e0]);
      gl_lds16(&W[(size_t)(n0 + r1) * 1024 + kn + c1], &Bs[nb][e1]);
    }
    const u16* Ab = &As[ks & 1][0];
    const u16* Bb = &Bs[ks & 1][0];
    bf16x8 a[4], b[4];
#pragma unroll
    for (int i = 0; i < 4; ++i)
      a[i] = *(const bf16x8*)&Ab[(wr * 64 + i * 16 + lr) * 32 + lg * 8];
#pragma unroll
    for (int j = 0; j < 4; ++j)
      b[j] = *(const bf16x8*)&Bb[(wc * 64 + j * 16 + lr) * 32 + lg * 8];
#pragma unroll
    for (int i = 0; i < 4; ++i)
#pragma unroll
      for (int j = 0; j < 4; ++j)
        acc[i][j] = __builtin_amdgcn_mfma_f32_16x16x32_bf16(a[i], b[j], acc[i][j], 0, 0, 0);
  }

#pragma unroll
  for (int i = 0; i < 4; ++i) {
#pragma unroll
    for (int j = 0; j < 4; ++j) {
#pragma unroll
      for (int r = 0; r < 4; ++r) {
        int m = m0 + wr * 64 + i * 16 + lg * 4 + r;
        int n = n0 + wc * 64 + j * 16 + lr;
        u16 bfv = f2bf(acc[i][j][r]);
        int bb = m >> 11, s = m & 2047, h = n >> 6, d = n & 63;
        if (which < 2) {
          u16* O = (which == 0) ? Qo : Ko;
          O[((size_t)(bb * 16 + h) * 2048 + s) * 64 + d] = bfv;
        } else {
          Vto[((size_t)(bb * 16 + h) * 64 + d) * 2048 + s] = bfv;
        }
      }
    }
  }
}

// XCD-chunked bijective swizzle for 1024 blocks (128 logical per XCD).
__device__ __forceinline__ int xcd_swz(int orig) {
  return (orig & 7) * 128 + (orig >> 3);
}

// ---------------- attention pass 1: softmax denom l per row ----------------
// LDS-staged K (dbuf, 1 barrier/tile), swapped mfma(K,Q): lane holds
// S[k=lg*4+r][q=lr] -> per-lane exp accumulation, 2 shfls at end.
__global__ void __launch_bounds__(256) attn_l(
    const u16* __restrict__ Qw, const u16* __restrict__ Kw, float* __restrict__ ml)
{
  __shared__ u16 Ks[2][64 * 64];

  const int t = threadIdx.x, lane = t & 63, w = t >> 6;
  const int lr = lane & 15, lg = lane >> 4;
  const int lin = xcd_swz(blockIdx.x);
  const int bh = lin >> 5, q0 = (lin & 31) * 64;
  const u16* Qbase = Qw + (size_t)bh * 2048 * 64;
  const u16* Kbase = Kw + (size_t)bh * 2048 * 64;

  const int qrow = q0 + w * 16 + lr;
  bf16x8 qa[2];
#pragma unroll
  for (int sl = 0; sl < 2; ++sl)
    qa[sl] = *(const bf16x8*)&Qbase[(size_t)qrow * 64 + sl * 32 + lg * 8];

  // staging coords (2 x 16B per thread; linear LDS dest, pre-swizzled source)
  const int o0 = t * 16, o1 = t * 16 + 4096;
  const int sr0 = o0 >> 7, ss0 = (o0 >> 4) & 7;
  const int sr1 = o1 >> 7, ss1 = (o1 >> 4) & 7;

  gl_lds16(&Kbase[(size_t)sr0 * 64 + ((ss0 ^ (sr0 & 7)) << 3)], (char*)&Ks[0][0] + o0);
  gl_lds16(&Kbase[(size_t)sr1 * 64 + ((ss1 ^ (sr1 & 7)) << 3)], (char*)&Ks[0][0] + o1);

  const f32x4 ZERO = {0.f, 0.f, 0.f, 0.f};
  float lacc = 0.f;

  for (int it = 0; it < 32; ++it) {
    __syncthreads();
    if (it + 1 < 32) {
      const int kn = (it + 1) * 64;
      const int nb = (it + 1) & 1;
      gl_lds16(&Kbase[(size_t)(kn + sr0) * 64 + ((ss0 ^ (sr0 & 7)) << 3)], (char*)&Ks[nb][0] + o0);
      gl_lds16(&Kbase[(size_t)(kn + sr1) * 64 + ((ss1 ^ (sr1 & 7)) << 3)], (char*)&Ks[nb][0] + o1);
    }
    const u16* Kb = &Ks[it & 1][0];

    f32x4 sacc[4];
#pragma unroll
    for (int jj = 0; jj < 4; ++jj) sacc[jj] = ZERO;
#pragma unroll
    for (int sl = 0; sl < 2; ++sl) {
#pragma unroll
      for (int jj = 0; jj < 4; ++jj) {
        int R = jj * 16 + lr;
        int gs = lg + sl * 4;
        bf16x8 kb = *(const bf16x8*)&Kb[R * 64 + ((gs ^ (R & 7)) << 3)];
        sacc[jj] = __builtin_amdgcn_mfma_f32_16x16x32_bf16(kb, qa[sl], sacc[jj], 0, 0, 0);
      }
    }
#pragma unroll
    for (int jj = 0; jj < 4; ++jj)
#pragma unroll
      for (int r = 0; r < 4; ++r)
        lacc += __expf(fminf(sacc[jj][r] * 0.125f, 30.f));
  }
  lacc += __shfl_xor(lacc, 16);
  lacc += __shfl_xor(lacc, 32);
  if (lg == 0) ml[(size_t)bh * 2048 + qrow] = lacc;
}

// ---------------- attention pass 2: attn write + PV -> ctx ----------------
// LDS-staged K AND V (dbuf); counted vmcnt(4)+raw barrier so the 537MB attn
// store stream is never drained. Swapped QK^T -> float4 attn stores,
// cvt_pk P->LDS -> PV with A=P(q rows), B=V(d rows).
__global__ void __launch_bounds__(256) attn_av(
    const u16* __restrict__ Qw, const u16* __restrict__ Kw, const u16* __restrict__ VTw,
    const float* __restrict__ ml, float* __restrict__ attn_out, float* __restrict__ ctx)
{
  __shared__ u16 Ks[2][64 * 64];
  __shared__ u16 Vs[2][64 * 64];
  __shared__ u16 Ps[4][16 * 72];

  const int t = threadIdx.x, lane = t & 63, w = t >> 6;
  const int lr = lane & 15, lg = lane >> 4;
  const int lin = xcd_swz(blockIdx.x);
  const int bh = lin >> 5, q0 = (lin & 31) * 64;
  const u16* Qbase = Qw + (size_t)bh * 2048 * 64;
  const u16* Kbase = Kw + (size_t)bh * 2048 * 64;
  const u16* VTbase = VTw + (size_t)bh * 64 * 2048;

  const int qrow = q0 + w * 16 + lr;
  bf16x8 qa[2];
#pragma unroll
  for (int sl = 0; sl < 2; ++sl)
    qa[sl] = *(const bf16x8*)&Qbase[(size_t)qrow * 64 + sl * 32 + lg * 8];

  const float linv = 1.f / ml[(size_t)bh * 2048 + qrow];
  float linv2[4];
#pragma unroll
  for (int r = 0; r < 4; ++r)
    linv2[r] = 1.f / ml[(size_t)bh * 2048 + q0 + w * 16 + lg * 4 + r];

  const f32x4 ZERO = {0.f, 0.f, 0.f, 0.f};
  f32x4 acc_o[4];
#pragma unroll
  for (int j = 0; j < 4; ++j) acc_o[j] = ZERO;

  float* arow = attn_out + ((size_t)bh * 2048 + qrow) * 2048;
  u16* Pw = &Ps[w][0];

  // staging coords (2 x 16B per thread per tensor)
  const int o0 = t * 16, o1 = t * 16 + 4096;
  const int sr0 = o0 >> 7, ss0 = (o0 >> 4) & 7;
  const int sr1 = o1 >> 7, ss1 = (o1 >> 4) & 7;

  // prologue: stage tile 0 (K rows = k, V rows = d)
  gl_lds16(&Kbase[(size_t)sr0 * 64 + ((ss0 ^ (sr0 & 7)) << 3)], (char*)&Ks[0][0] + o0);
  gl_lds16(&Kbase[(size_t)sr1 * 64 + ((ss1 ^ (sr1 & 7)) << 3)], (char*)&Ks[0][0] + o1);
  gl_lds16(&VTbase[(size_t)sr0 * 2048 + ((ss0 ^ (sr0 & 7)) << 3)], (char*)&Vs[0][0] + o0);
  gl_lds16(&VTbase[(size_t)sr1 * 2048 + ((ss1 ^ (sr1 & 7)) << 3)], (char*)&Vs[0][0] + o1);
  __syncthreads();

  for (int it = 0; it < 32; ++it) {
    const int kt = it * 64;
    if (it + 1 < 32) {                    // stage next tile into other buffer
      const int kn = kt + 64;
      const int nb = (it + 1) & 1;
      gl_lds16(&Kbase[(size_t)(kn + sr0) * 64 + ((ss0 ^ (sr0 & 7)) << 3)], (char*)&Ks[nb][0] + o0);
      gl_lds16(&Kbase[(size_t)(kn + sr1) * 64 + ((ss1 ^ (sr1 & 7)) << 3)], (char*)&Ks[nb][0] + o1);
      gl_lds16(&VTbase[(size_t)sr0 * 2048 + kn + ((ss0 ^ (sr0 & 7)) << 3)], (char*)&Vs[nb][0] + o0);
      gl_lds16(&VTbase[(size_t)sr1 * 2048 + kn + ((ss1 ^ (sr1 & 7)) << 3)], (char*)&Vs[nb][0] + o1);
    }
    const u16* Kb = &Ks[it & 1][0];
    const u16* Vb = &Vs[it & 1][0];

    // S^T tile: lane holds S[k=kt+jj*16+lg*4+r][q=lr]
    f32x4 sacc[4];
#pragma unroll
    for (int jj = 0; jj < 4; ++jj) sacc[jj] = ZERO;
#pragma unroll
    for (int sl = 0; sl < 2; ++sl) {
#pragma unroll
      for (int jj = 0; jj < 4; ++jj) {
        int R = jj * 16 + lr;
        int gs = lg + sl * 4;
        bf16x8 kb = *(const bf16x8*)&Kb[R * 64 + ((gs ^ (R & 7)) << 3)];
        sacc[jj] = __builtin_amdgcn_mfma_f32_16x16x32_bf16(kb, qa[sl], sacc[jj], 0, 0, 0);
      }
    }

    // exp, float4 attn store, P -> per-wave LDS (8B x4)
#pragma unroll
    for (int jj = 0; jj < 4; ++jj) {
      f32x4 e;
#pragma unroll
      for (int r = 0; r < 4; ++r)
        e[r] = __expf(fminf(sacc[jj][r] * 0.125f, 30.f));
      f32x4 st = e * linv;
      *(f32x4*)&arow[kt + jj * 16 + lg * 4] = st;
      u32 p01 = cvt_pk_bf16(e[0], e[1]);
      u32 p23 = cvt_pk_bf16(e[2], e[3]);
      *(uint2*)&Pw[lr * 72 + jj * 16 + lg * 4] = make_uint2(p01, p23);
    }
    asm volatile("s_waitcnt lgkmcnt(0)" ::: "memory");
    __builtin_amdgcn_sched_barrier(0);

    // PV: A = P (rows q), B = V (rows d)
    bf16x8 pa[2];
#pragma unroll
    for (int sl = 0; sl < 2; ++sl)
      pa[sl] = *(const bf16x8*)&Pw[lr * 72 + sl * 32 + lg * 8];
#pragma unroll
    for (int jj = 0; jj < 4; ++jj) {
#pragma unroll
      for (int sl = 0; sl < 2; ++sl) {
        int R = jj * 16 + lr;
        int gs = lg + sl * 4;
        bf16x8 vb = *(const bf16x8*)&Vb[R * 64 + ((gs ^ (R & 7)) << 3)];
        acc_o[jj] = __builtin_amdgcn_mfma_f32_16x16x32_bf16(pa[sl], vb, acc_o[jj], 0, 0, 0);
      }
    }

    if (it + 1 < 32) {
      // wait staging gl_lds (4 oldest) WITHOUT draining the attn stores
      __builtin_amdgcn_sched_barrier(0);
      asm volatile("s_waitcnt vmcnt(4)" ::: "memory");
      __builtin_amdgcn_s_barrier();
      __builtin_amdgcn_sched_barrier(0);
    }
  }

  const int bb = bh >> 4, h = bh & 15;
#pragma unroll
  for (int jj = 0; jj < 4; ++jj) {
#pragma unroll
    for (int r = 0; r < 4; ++r) {
      int srow = q0 + w * 16 + lg * 4 + r;
      ctx[((size_t)bb * 2048 + srow) * 1024 + h * 64 + jj * 16 + lr] = acc_o[jj][r] * linv2[r];
    }
  }
}

// ---------------- residual + LayerNorm ----------------
__global__ void __launch_bounds__(256) ln_kernel(
    const float* __restrict__ ctx, const float* __restrict__ res, float* __restrict__ out)
{
  __shared__ float red[8];
  int row = blockIdx.x;
  int t = threadIdx.x;
  int lane = t & 63, w = t >> 6;
  size_t base = (size_t)row * 1024 + t * 4;
  float4 c = *(const float4*)&ctx[base];
  float4 rs = *(const float4*)&res[base];
  float x0 = c.x + rs.x, x1 = c.y + rs.y, x2 = c.z + rs.z, x3 = c.w + rs.w;
  float s = x0 + x1 + x2 + x3;
  float q = x0 * x0 + x1 * x1 + x2 * x2 + x3 * x3;
#pragma unroll
  for (int off = 1; off < 64; off <<= 1) {
    s += __shfl_xor(s, off);
    q += __shfl_xor(q, off);
  }
  if (lane == 0) { red[w] = s; red[w + 4] = q; }
  __syncthreads();
  s = red[0] + red[1] + red[2] + red[3];
  q = red[4] + red[5] + red[6] + red[7];
  float mu = s * (1.f / 1024.f);
  float var = q * (1.f / 1024.f) - mu * mu;
  float inv = rsqrtf(var + 1e-5f);
  float4 o;
  o.x = (x0 - mu) * inv; o.y = (x1 - mu) * inv; o.z = (x2 - mu) * inv; o.w = (x3 - mu) * inv;
  *(float4*)&out[base] = o;
}

extern "C" void kernel_launch(void* const* d_in, const int* in_sizes, int n_in,
                              void* d_out, int out_size, void* d_ws, size_t ws_size,
                              hipStream_t stream) {
  (void)in_sizes; (void)n_in; (void)out_size; (void)ws_size;
  const float* inQ = (const float*)d_in[0];
  const float* inK = (const float*)d_in[1];
  const float* inV = (const float*)d_in[2];
  const float* wQ  = (const float*)d_in[3];
  const float* wK  = (const float*)d_in[4];
  const float* wV  = (const float*)d_in[5];

  char* ws = (char*)d_ws;
  const size_t NELEM = 4096u * 1024u;
  u16* Qbf  = (u16*)(ws);                        // 8MB  [b,h,s,d] bf16
  u16* Kbf  = (u16*)(ws + (8ull << 20));         // 8MB
  u16* VTbf = (u16*)(ws + (16ull << 20));        // 8MB  [b,h,d,s] bf16
  u16* Xq   = (u16*)(ws + (24ull << 20));
  u16* Xk   = (u16*)(ws + (32ull << 20));
  u16* Xv   = (u16*)(ws + (40ull << 20));
  u16* Wqb  = (u16*)(ws + (48ull << 20));
  u16* Wkb  = (u16*)(ws + (50ull << 20));
  u16* Wvb  = (u16*)(ws + (52ull << 20));
  float* ml  = (float*)(ws + (54ull << 20));     // 256KB (l per row)
  float* ctx = (float*)(ws + (56ull << 20));     // 16MB f32 [b,s,1024]

  float* out  = (float*)d_out;
  float* attn = out + NELEM;

  dim3 b256(256);
  cvt3_kernel<<<dim3(4096, 3), b256, 0, stream>>>(inQ, inK, inV, Xq, Xk, Xv, (int)(NELEM / 4));
  cvt3_kernel<<<dim3(1024, 3), b256, 0, stream>>>(wQ, wK, wV, Wqb, Wkb, Wvb, 1048576 / 4);

  proj_gemm<<<dim3(8, 32, 3), b256, 0, stream>>>(Xq, Xk, Xv, Wqb, Wkb, Wvb, Qbf, Kbf, VTbf);

  attn_l<<<dim3(1024), b256, 0, stream>>>(Qbf, Kbf, ml);
  attn_av<<<dim3(1024), b256, 0, stream>>>(Qbf, Kbf, VTbf, ml, attn, ctx);

  ln_kernel<<<dim3(4096), b256, 0, stream>>>(ctx, inQ, out);
}

// Round 5
// 285.688 us; speedup vs baseline: 1.7514x; 1.1093x over previous
//
#include <hip/hip_runtime.h>

typedef unsigned int u32;
typedef unsigned short u16;
typedef __attribute__((ext_vector_type(8))) __bf16 bf16x8;
typedef __attribute__((ext_vector_type(4))) float f32x4;

#define AS1 __attribute__((address_space(1)))
#define AS3 __attribute__((address_space(3)))

__device__ __forceinline__ void gl_lds16(const void* g, void* l) {
  __builtin_amdgcn_global_load_lds((const AS1 void*)g, (AS3 void*)l, 16, 0, 0);
}

__device__ __forceinline__ u16 f2bf(float f) {
  union { float f; u32 u; } v; v.f = f;
  u32 r = v.u + 0x7fffu + ((v.u >> 16) & 1u);
  return (u16)(r >> 16);
}

__device__ __forceinline__ u32 cvt_pk_bf16(float a, float b) {
  u32 r;
  asm("v_cvt_pk_bf16_f32 %0, %1, %2" : "=v"(r) : "v"(a), "v"(b));
  return r;
}

// ---------------- f32 -> bf16 conversion (3 arrays per launch) ----------------
__global__ void cvt3_kernel(const float* __restrict__ a, const float* __restrict__ b,
                            const float* __restrict__ c, u16* __restrict__ oa,
                            u16* __restrict__ ob, u16* __restrict__ oc, int n4) {
  const float* in = (blockIdx.y == 0) ? a : (blockIdx.y == 1) ? b : c;
  u16* out = (blockIdx.y == 0) ? oa : (blockIdx.y == 1) ? ob : oc;
  int i = blockIdx.x * blockDim.x + threadIdx.x;
  if (i >= n4) return;
  float4 v = ((const float4*)in)[i];
  ushort4 o;
  o.x = f2bf(v.x); o.y = f2bf(v.y); o.z = f2bf(v.z); o.w = f2bf(v.w);
  ((ushort4*)out)[i] = o;
}

// ---------------- projection GEMM: C[m,n] = sum_k X[m,k] W[n,k] ----------------
// 128x128 tile, BK=32, 4 waves, 2-phase prefetch dbuf (R4-proven, unchanged).
__global__ void __launch_bounds__(256) proj_gemm(
    const u16* __restrict__ Xq, const u16* __restrict__ Xk, const u16* __restrict__ Xv,
    const u16* __restrict__ Wq, const u16* __restrict__ Wk, const u16* __restrict__ Wv,
    u16* __restrict__ Qo, u16* __restrict__ Ko, u16* __restrict__ Vto)
{
  const int which = blockIdx.z;
  const u16* X = (which == 0) ? Xq : (which == 1) ? Xk : Xv;
  const u16* W = (which == 0) ? Wq : (which == 1) ? Wk : Wv;

  __shared__ u16 As[2][128 * 32];
  __shared__ u16 Bs[2][128 * 32];

  const int t = threadIdx.x;
  const int lane = t & 63;
  const int w = t >> 6;
  const int wr = w >> 1, wc = w & 1;
  const int lr = lane & 15, lg = lane >> 4;
  const int m0 = blockIdx.y * 128, n0 = blockIdx.x * 128;

  const int e0 = t * 8, e1 = t * 8 + 2048;
  const int r0 = e0 >> 5, c0 = e0 & 31, r1 = e1 >> 5, c1 = e1 & 31;

  const f32x4 ZERO = {0.f, 0.f, 0.f, 0.f};
  f32x4 acc[4][4];
  for (int i = 0; i < 4; ++i)
    for (int j = 0; j < 4; ++j) acc[i][j] = ZERO;

  gl_lds16(&X[(size_t)(m0 + r0) * 1024 + c0], &As[0][e0]);
  gl_lds16(&X[(size_t)(m0 + r1) * 1024 + c1], &As[0][e1]);
  gl_lds16(&W[(size_t)(n0 + r0) * 1024 + c0], &Bs[0][e0]);
  gl_lds16(&W[(size_t)(n0 + r1) * 1024 + c1], &Bs[0][e1]);

  for (int ks = 0; ks < 32; ++ks) {
    __syncthreads();
    if (ks + 1 < 32) {
      int kn = (ks + 1) * 32;
      int nb = (ks + 1) & 1;
      gl_lds16(&X[(size_t)(m0 + r0) * 1024 + kn + c0], &As[nb][e0]);
      gl_lds16(&X[(size_t)(m0 + r1) * 1024 + kn + c1], &As[nb][e1]);
      gl_lds16(&W[(size_t)(n0 + r0) * 1024 + kn + c0], &Bs[nb][e0]);
      gl_lds16(&W[(size_t)(n0 + r1) * 1024 + kn + c1], &Bs[nb][e1]);
    }
    const u16* Ab = &As[ks & 1][0];
    const u16* Bb = &Bs[ks & 1][0];
    bf16x8 a[4], b[4];
#pragma unroll
    for (int i = 0; i < 4; ++i)
      a[i] = *(const bf16x8*)&Ab[(wr * 64 + i * 16 + lr) * 32 + lg * 8];
#pragma unroll
    for (int j = 0; j < 4; ++j)
      b[j] = *(const bf16x8*)&Bb[(wc * 64 + j * 16 + lr) * 32 + lg * 8];
#pragma unroll
    for (int i = 0; i < 4; ++i)
#pragma unroll
      for (int j = 0; j < 4; ++j)
        acc[i][j] = __builtin_amdgcn_mfma_f32_16x16x32_bf16(a[i], b[j], acc[i][j], 0, 0, 0);
  }

#pragma unroll
  for (int i = 0; i < 4; ++i) {
#pragma unroll
    for (int j = 0; j < 4; ++j) {
#pragma unroll
      for (int r = 0; r < 4; ++r) {
        int m = m0 + wr * 64 + i * 16 + lg * 4 + r;
        int n = n0 + wc * 64 + j * 16 + lr;
        u16 bfv = f2bf(acc[i][j][r]);
        int bb = m >> 11, s = m & 2047, h = n >> 6, d = n & 63;
        if (which < 2) {
          u16* O = (which == 0) ? Qo : Ko;
          O[((size_t)(bb * 16 + h) * 2048 + s) * 64 + d] = bfv;
        } else {
          Vto[((size_t)(bb * 16 + h) * 64 + d) * 2048 + s] = bfv;
        }
      }
    }
  }
}

// ---------------- fused attention: denom + attn write + PV ----------------
// 8 waves, QBLK=128, KVBLK=64. Phase 1: swapped mfma(K,Q), per-lane exp
// accumulation -> l via 2 shfls (no global ml). Phase 2: R4 attn_av pattern
// (counted vmcnt, raw barrier -> the 537MB store stream never drains).
__global__ void __launch_bounds__(512, 4) attn_fused(
    const u16* __restrict__ Qw, const u16* __restrict__ Kw, const u16* __restrict__ VTw,
    float* __restrict__ attn_out, float* __restrict__ ctx)
{
  __shared__ u16 Ks[2][64 * 64];   // 16KB
  __shared__ u16 Vs[2][64 * 64];   // 16KB
  __shared__ u16 Ps[8][16 * 72];   // 18KB, per-wave P, stride 144B

  const int t = threadIdx.x, lane = t & 63, w = t >> 6;
  const int lr = lane & 15, lg = lane >> 4;
  const int orig = blockIdx.x;
  const int lin = (orig & 7) * 64 + (orig >> 3);   // XCD-chunked bijective (512=8*64)
  const int bh = lin >> 4, q0 = (lin & 15) * 128;

  const u16* Qbase = Qw + (size_t)bh * 2048 * 64;
  const u16* Kbase = Kw + (size_t)bh * 2048 * 64;
  const u16* VTbase = VTw + (size_t)bh * 64 * 2048;

  const int qrow = q0 + w * 16 + lr;
  bf16x8 qa[2];
#pragma unroll
  for (int sl = 0; sl < 2; ++sl)
    qa[sl] = *(const bf16x8*)&Qbase[(size_t)qrow * 64 + sl * 32 + lg * 8];

  // staging coords: ONE 16B chunk per thread (512 thr x 16B = 8KB tile).
  // linear LDS dest, pre-swizzled global source (slot s of row r <- s^(r&7)).
  const int o = t * 16;
  const int sr = o >> 7;
  const int sg = (((o >> 4) & 7) ^ (sr & 7)) << 3;

  const f32x4 ZERO = {0.f, 0.f, 0.f, 0.f};

  // ================= phase 1: softmax denominator =================
  gl_lds16(&Kbase[(size_t)sr * 64 + sg], (char*)&Ks[0][0] + o);
  float lacc = 0.f;
  for (int it = 0; it < 32; ++it) {
    __syncthreads();
    if (it + 1 < 32)
      gl_lds16(&Kbase[(size_t)((it + 1) * 64 + sr) * 64 + sg],
               (char*)&Ks[(it + 1) & 1][0] + o);
    const u16* Kb = &Ks[it & 1][0];
    f32x4 sacc[4];
#pragma unroll
    for (int jj = 0; jj < 4; ++jj) sacc[jj] = ZERO;
#pragma unroll
    for (int sl = 0; sl < 2; ++sl) {
#pragma unroll
      for (int jj = 0; jj < 4; ++jj) {
        int R = jj * 16 + lr;
        int gs = lg + sl * 4;
        bf16x8 kb = *(const bf16x8*)&Kb[R * 64 + ((gs ^ (R & 7)) << 3)];
        sacc[jj] = __builtin_amdgcn_mfma_f32_16x16x32_bf16(kb, qa[sl], sacc[jj], 0, 0, 0);
      }
    }
#pragma unroll
    for (int jj = 0; jj < 4; ++jj)
#pragma unroll
      for (int r = 0; r < 4; ++r)
        lacc += __expf(fminf(sacc[jj][r] * 0.125f, 30.f));
  }
  lacc += __shfl_xor(lacc, 16);
  lacc += __shfl_xor(lacc, 32);               // l for q = qrow (uniform over lg)
  const float linv = 1.f / lacc;

  // ================= phase 2: attn write + PV =================
  // prologue staging overlaps the phase-1 tail of other waves
  gl_lds16(&Kbase[(size_t)sr * 64 + sg], (char*)&Ks[0][0] + o);
  gl_lds16(&VTbase[(size_t)sr * 2048 + sg], (char*)&Vs[0][0] + o);
  __syncthreads();

  f32x4 acc_o[4];
#pragma unroll
  for (int j = 0; j < 4; ++j) acc_o[j] = ZERO;

  float* arow = attn_out + ((size_t)bh * 2048 + qrow) * 2048;
  u16* Pw = &Ps[w][0];

  for (int it = 0; it < 32; ++it) {
    const int kt = it * 64;
    if (it + 1 < 32) {
      const int nb = (it + 1) & 1;
      gl_lds16(&Kbase[(size_t)(kt + 64 + sr) * 64 + sg], (char*)&Ks[nb][0] + o);
      gl_lds16(&VTbase[(size_t)sr * 2048 + kt + 64 + sg], (char*)&Vs[nb][0] + o);
    }
    const u16* Kb = &Ks[it & 1][0];
    const u16* Vb = &Vs[it & 1][0];

    // S^T tile: lane holds S[k=kt+jj*16+lg*4+r][q=qrow]
    f32x4 sacc[4];
#pragma unroll
    for (int jj = 0; jj < 4; ++jj) sacc[jj] = ZERO;
#pragma unroll
    for (int sl = 0; sl < 2; ++sl) {
#pragma unroll
      for (int jj = 0; jj < 4; ++jj) {
        int R = jj * 16 + lr;
        int gs = lg + sl * 4;
        bf16x8 kb = *(const bf16x8*)&Kb[R * 64 + ((gs ^ (R & 7)) << 3)];
        sacc[jj] = __builtin_amdgcn_mfma_f32_16x16x32_bf16(kb, qa[sl], sacc[jj], 0, 0, 0);
      }
    }

    // exp, float4 attn store, P -> per-wave LDS (8B x4)
#pragma unroll
    for (int jj = 0; jj < 4; ++jj) {
      f32x4 e;
#pragma unroll
      for (int r = 0; r < 4; ++r)
        e[r] = __expf(fminf(sacc[jj][r] * 0.125f, 30.f));
      f32x4 st = e * linv;
      *(f32x4*)&arow[kt + jj * 16 + lg * 4] = st;
      u32 p01 = cvt_pk_bf16(e[0], e[1]);
      u32 p23 = cvt_pk_bf16(e[2], e[3]);
      *(uint2*)&Pw[lr * 72 + jj * 16 + lg * 4] = make_uint2(p01, p23);
    }
    asm volatile("s_waitcnt lgkmcnt(0)" ::: "memory");
    __builtin_amdgcn_sched_barrier(0);

    // PV: A = P (rows q), B = V (rows d)
    bf16x8 pa[2];
#pragma unroll
    for (int sl = 0; sl < 2; ++sl)
      pa[sl] = *(const bf16x8*)&Pw[lr * 72 + sl * 32 + lg * 8];
#pragma unroll
    for (int jj = 0; jj < 4; ++jj) {
#pragma unroll
      for (int sl = 0; sl < 2; ++sl) {
        int R = jj * 16 + lr;
        int gs = lg + sl * 4;
        bf16x8 vb = *(const bf16x8*)&Vb[R * 64 + ((gs ^ (R & 7)) << 3)];
        acc_o[jj] = __builtin_amdgcn_mfma_f32_16x16x32_bf16(pa[sl], vb, acc_o[jj], 0, 0, 0);
      }
    }

    if (it + 1 < 32) {
      // drain only the 2 staging gl_lds (4 newest = this tile's attn stores stay in flight)
      __builtin_amdgcn_sched_barrier(0);
      asm volatile("s_waitcnt vmcnt(4)" ::: "memory");
      __builtin_amdgcn_s_barrier();
      __builtin_amdgcn_sched_barrier(0);
    }
  }

  // epilogue: ctx = O / l ; l for row q=w*16+lg*4+r fetched via shfl
  const int bb = bh >> 4, h = bh & 15;
  float linv2[4];
#pragma unroll
  for (int r = 0; r < 4; ++r)
    linv2[r] = 1.f / __shfl(lacc, lg * 4 + r);
#pragma unroll
  for (int jj = 0; jj < 4; ++jj) {
#pragma unroll
    for (int r = 0; r < 4; ++r) {
      int srow = q0 + w * 16 + lg * 4 + r;
      ctx[((size_t)bb * 2048 + srow) * 1024 + h * 64 + jj * 16 + lr] = acc_o[jj][r] * linv2[r];
    }
  }
}

// ---------------- residual + LayerNorm ----------------
__global__ void __launch_bounds__(256) ln_kernel(
    const float* __restrict__ ctx, const float* __restrict__ res, float* __restrict__ out)
{
  __shared__ float red[8];
  int row = blockIdx.x;
  int t = threadIdx.x;
  int lane = t & 63, w = t >> 6;
  size_t base = (size_t)row * 1024 + t * 4;
  float4 c = *(const float4*)&ctx[base];
  float4 rs = *(const float4*)&res[base];
  float x0 = c.x + rs.x, x1 = c.y + rs.y, x2 = c.z + rs.z, x3 = c.w + rs.w;
  float s = x0 + x1 + x2 + x3;
  float q = x0 * x0 + x1 * x1 + x2 * x2 + x3 * x3;
#pragma unroll
  for (int off = 1; off < 64; off <<= 1) {
    s += __shfl_xor(s, off);
    q += __shfl_xor(q, off);
  }
  if (lane == 0) { red[w] = s; red[w + 4] = q; }
  __syncthreads();
  s = red[0] + red[1] + red[2] + red[3];
  q = red[4] + red[5] + red[6] + red[7];
  float mu = s * (1.f / 1024.f);
  float var = q * (1.f / 1024.f) - mu * mu;
  float inv = rsqrtf(var + 1e-5f);
  float4 o;
  o.x = (x0 - mu) * inv; o.y = (x1 - mu) * inv; o.z = (x2 - mu) * inv; o.w = (x3 - mu) * inv;
  *(float4*)&out[base] = o;
}

extern "C" void kernel_launch(void* const* d_in, const int* in_sizes, int n_in,
                              void* d_out, int out_size, void* d_ws, size_t ws_size,
                              hipStream_t stream) {
  (void)in_sizes; (void)n_in; (void)out_size; (void)ws_size;
  const float* inQ = (const float*)d_in[0];
  const float* inK = (const float*)d_in[1];
  const float* inV = (const float*)d_in[2];
  const float* wQ  = (const float*)d_in[3];
  const float* wK  = (const float*)d_in[4];
  const float* wV  = (const float*)d_in[5];

  char* ws = (char*)d_ws;
  const size_t NELEM = 4096u * 1024u;
  u16* Qbf  = (u16*)(ws);                        // 8MB  [b,h,s,d] bf16
  u16* Kbf  = (u16*)(ws + (8ull << 20));         // 8MB
  u16* VTbf = (u16*)(ws + (16ull << 20));        // 8MB  [b,h,d,s] bf16
  u16* Xq   = (u16*)(ws + (24ull << 20));
  u16* Xk   = (u16*)(ws + (32ull << 20));
  u16* Xv   = (u16*)(ws + (40ull << 20));
  u16* Wqb  = (u16*)(ws + (48ull << 20));
  u16* Wkb  = (u16*)(ws + (50ull << 20));
  u16* Wvb  = (u16*)(ws + (52ull << 20));
  float* ctx = (float*)(ws + (56ull << 20));     // 16MB f32 [b,s,1024]

  float* out  = (float*)d_out;
  float* attn = out + NELEM;

  dim3 b256(256);
  cvt3_kernel<<<dim3(4096, 3), b256, 0, stream>>>(inQ, inK, inV, Xq, Xk, Xv, (int)(NELEM / 4));
  cvt3_kernel<<<dim3(1024, 3), b256, 0, stream>>>(wQ, wK, wV, Wqb, Wkb, Wvb, 1048576 / 4);

  proj_gemm<<<dim3(8, 32, 3), b256, 0, stream>>>(Xq, Xk, Xv, Wqb, Wkb, Wvb, Qbf, Kbf, VTbf);

  attn_fused<<<dim3(512), dim3(512), 0, stream>>>(Qbf, Kbf, VTbf, attn, ctx);

  ln_kernel<<<dim3(4096), b256, 0, stream>>>(ctx, inQ, out);
}

// Round 6
// 285.647 us; speedup vs baseline: 1.7516x; 1.0001x over previous
//
#include <hip/hip_runtime.h>

typedef unsigned int u32;
typedef unsigned short u16;
typedef __attribute__((ext_vector_type(8))) __bf16 bf16x8;
typedef __attribute__((ext_vector_type(4))) float f32x4;

#define AS1 __attribute__((address_space(1)))
#define AS3 __attribute__((address_space(3)))

__device__ __forceinline__ void gl_lds16(const void* g, void* l) {
  __builtin_amdgcn_global_load_lds((const AS1 void*)g, (AS3 void*)l, 16, 0, 0);
}

__device__ __forceinline__ u16 f2bf(float f) {
  union { float f; u32 u; } v; v.f = f;
  u32 r = v.u + 0x7fffu + ((v.u >> 16) & 1u);
  return (u16)(r >> 16);
}

__device__ __forceinline__ float bf2f(u16 b) {
  union { u32 u; float f; } v; v.u = ((u32)b) << 16; return v.f;
}

__device__ __forceinline__ u32 cvt_pk_bf16(float a, float b) {
  u32 r;
  asm("v_cvt_pk_bf16_f32 %0, %1, %2" : "=v"(r) : "v"(a), "v"(b));
  return r;
}

// ---------------- f32 -> bf16 conversion (3 arrays per launch) ----------------
__global__ void cvt3_kernel(const float* __restrict__ a, const float* __restrict__ b,
                            const float* __restrict__ c, u16* __restrict__ oa,
                            u16* __restrict__ ob, u16* __restrict__ oc, int n4) {
  const float* in = (blockIdx.y == 0) ? a : (blockIdx.y == 1) ? b : c;
  u16* out = (blockIdx.y == 0) ? oa : (blockIdx.y == 1) ? ob : oc;
  int i = blockIdx.x * blockDim.x + threadIdx.x;
  if (i >= n4) return;
  float4 v = ((const float4*)in)[i];
  ushort4 o;
  o.x = f2bf(v.x); o.y = f2bf(v.y); o.z = f2bf(v.z); o.w = f2bf(v.w);
  ((ushort4*)out)[i] = o;
}

// ---------------- projection GEMM: C[m,n] = sum_k X[m,k] W[n,k] ----------------
// 128x128 tile, BK=32, 4 waves, 2-phase prefetch dbuf (R4-proven, unchanged).
__global__ void __launch_bounds__(256) proj_gemm(
    const u16* __restrict__ Xq, const u16* __restrict__ Xk, const u16* __restrict__ Xv,
    const u16* __restrict__ Wq, const u16* __restrict__ Wk, const u16* __restrict__ Wv,
    u16* __restrict__ Qo, u16* __restrict__ Ko, u16* __restrict__ Vto)
{
  const int which = blockIdx.z;
  const u16* X = (which == 0) ? Xq : (which == 1) ? Xk : Xv;
  const u16* W = (which == 0) ? Wq : (which == 1) ? Wk : Wv;

  __shared__ u16 As[2][128 * 32];
  __shared__ u16 Bs[2][128 * 32];

  const int t = threadIdx.x;
  const int lane = t & 63;
  const int w = t >> 6;
  const int wr = w >> 1, wc = w & 1;
  const int lr = lane & 15, lg = lane >> 4;
  const int m0 = blockIdx.y * 128, n0 = blockIdx.x * 128;

  const int e0 = t * 8, e1 = t * 8 + 2048;
  const int r0 = e0 >> 5, c0 = e0 & 31, r1 = e1 >> 5, c1 = e1 & 31;

  const f32x4 ZERO = {0.f, 0.f, 0.f, 0.f};
  f32x4 acc[4][4];
  for (int i = 0; i < 4; ++i)
    for (int j = 0; j < 4; ++j) acc[i][j] = ZERO;

  gl_lds16(&X[(size_t)(m0 + r0) * 1024 + c0], &As[0][e0]);
  gl_lds16(&X[(size_t)(m0 + r1) * 1024 + c1], &As[0][e1]);
  gl_lds16(&W[(size_t)(n0 + r0) * 1024 + c0], &Bs[0][e0]);
  gl_lds16(&W[(size_t)(n0 + r1) * 1024 + c1], &Bs[0][e1]);

  for (int ks = 0; ks < 32; ++ks) {
    __syncthreads();
    if (ks + 1 < 32) {
      int kn = (ks + 1) * 32;
      int nb = (ks + 1) & 1;
      gl_lds16(&X[(size_t)(m0 + r0) * 1024 + kn + c0], &As[nb][e0]);
      gl_lds16(&X[(size_t)(m0 + r1) * 1024 + kn + c1], &As[nb][e1]);
      gl_lds16(&W[(size_t)(n0 + r0) * 1024 + kn + c0], &Bs[nb][e0]);
      gl_lds16(&W[(size_t)(n0 + r1) * 1024 + kn + c1], &Bs[nb][e1]);
    }
    const u16* Ab = &As[ks & 1][0];
    const u16* Bb = &Bs[ks & 1][0];
    bf16x8 a[4], b[4];
#pragma unroll
    for (int i = 0; i < 4; ++i)
      a[i] = *(const bf16x8*)&Ab[(wr * 64 + i * 16 + lr) * 32 + lg * 8];
#pragma unroll
    for (int j = 0; j < 4; ++j)
      b[j] = *(const bf16x8*)&Bb[(wc * 64 + j * 16 + lr) * 32 + lg * 8];
#pragma unroll
    for (int i = 0; i < 4; ++i)
#pragma unroll
      for (int j = 0; j < 4; ++j)
        acc[i][j] = __builtin_amdgcn_mfma_f32_16x16x32_bf16(a[i], b[j], acc[i][j], 0, 0, 0);
  }

#pragma unroll
  for (int i = 0; i < 4; ++i) {
#pragma unroll
    for (int j = 0; j < 4; ++j) {
#pragma unroll
      for (int r = 0; r < 4; ++r) {
        int m = m0 + wr * 64 + i * 16 + lg * 4 + r;
        int n = n0 + wc * 64 + j * 16 + lr;
        u16 bfv = f2bf(acc[i][j][r]);
        int bb = m >> 11, s = m & 2047, h = n >> 6, d = n & 63;
        if (which < 2) {
          u16* O = (which == 0) ? Qo : Ko;
          O[((size_t)(bb * 16 + h) * 2048 + s) * 64 + d] = bfv;
        } else {
          Vto[((size_t)(bb * 16 + h) * 64 + d) * 2048 + s] = bfv;
        }
      }
    }
  }
}

// ---------------- fused attention: denom + attn write + PV ----------------
// 8 waves, QBLK=128, KVBLK=64, triple-buffered staging with prefetch
// distance 2. Counted vmcnt barriers retire ONLY the needed staging ops;
// the 537MB attn store backlog (4+4 stores newer than the awaited stage)
// never blocks a barrier. Attn stores are non-temporal to keep K/V in L2.
__global__ void __launch_bounds__(512, 4) attn_fused(
    const u16* __restrict__ Qw, const u16* __restrict__ Kw, const u16* __restrict__ VTw,
    float* __restrict__ attn_out, u16* __restrict__ ctx)
{
  __shared__ u16 Ks[3][64 * 64];   // 24KB
  __shared__ u16 Vs[3][64 * 64];   // 24KB
  __shared__ u16 Ps[8][16 * 72];   // 18KB, per-wave P, stride 144B

  const int t = threadIdx.x, lane = t & 63, w = t >> 6;
  const int lr = lane & 15, lg = lane >> 4;
  const int orig = blockIdx.x;
  const int lin = (orig & 7) * 64 + (orig >> 3);   // XCD-chunked bijective (512=8*64)
  const int bh = lin >> 4, q0 = (lin & 15) * 128;

  const u16* Qbase = Qw + (size_t)bh * 2048 * 64;
  const u16* Kbase = Kw + (size_t)bh * 2048 * 64;
  const u16* VTbase = VTw + (size_t)bh * 64 * 2048;

  const int qrow = q0 + w * 16 + lr;
  bf16x8 qa[2];
#pragma unroll
  for (int sl = 0; sl < 2; ++sl)
    qa[sl] = *(const bf16x8*)&Qbase[(size_t)qrow * 64 + sl * 32 + lg * 8];

  // staging coords: ONE 16B chunk per thread (512 thr x 16B = 8KB tile).
  // linear LDS dest, pre-swizzled global source (slot s of row r <- s^(r&7)).
  const int o = t * 16;
  const int sr = o >> 7;
  const int sg = (((o >> 4) & 7) ^ (sr & 7)) << 3;

  const f32x4 ZERO = {0.f, 0.f, 0.f, 0.f};

  // ================= phase 1: softmax denominator =================
  gl_lds16(&Kbase[(size_t)sr * 64 + sg], (char*)&Ks[0][0] + o);
  gl_lds16(&Kbase[(size_t)(64 + sr) * 64 + sg], (char*)&Ks[1][0] + o);
  __syncthreads();

  float lacc = 0.f;
  for (int it = 0; it < 32; ++it) {
    if (it + 2 < 32)
      gl_lds16(&Kbase[(size_t)((it + 2) * 64 + sr) * 64 + sg],
               (char*)&Ks[(it + 2) % 3][0] + o);
    const u16* Kb = &Ks[it % 3][0];
    f32x4 sacc[4];
#pragma unroll
    for (int jj = 0; jj < 4; ++jj) sacc[jj] = ZERO;
#pragma unroll
    for (int sl = 0; sl < 2; ++sl) {
#pragma unroll
      for (int jj = 0; jj < 4; ++jj) {
        int R = jj * 16 + lr;
        int gs = lg + sl * 4;
        bf16x8 kb = *(const bf16x8*)&Kb[R * 64 + ((gs ^ (R & 7)) << 3)];
        sacc[jj] = __builtin_amdgcn_mfma_f32_16x16x32_bf16(kb, qa[sl], sacc[jj], 0, 0, 0);
      }
    }
#pragma unroll
    for (int jj = 0; jj < 4; ++jj)
#pragma unroll
      for (int r = 0; r < 4; ++r)
        lacc += __expf(fminf(sacc[jj][r] * 0.125f, 30.f));

    if (it < 31) {
      __builtin_amdgcn_sched_barrier(0);
      if (it == 30) { asm volatile("s_waitcnt vmcnt(0)" ::: "memory"); }
      else         { asm volatile("s_waitcnt vmcnt(2)" ::: "memory"); }
      __builtin_amdgcn_s_barrier();
      __builtin_amdgcn_sched_barrier(0);
    }
  }
  lacc += __shfl_xor(lacc, 16);
  lacc += __shfl_xor(lacc, 32);               // l for q = qrow (uniform over lg)
  const float linv = 1.f / lacc;

  // ================= phase 2: attn write + PV =================
  __syncthreads();                            // all phase-1 LDS reads done
  gl_lds16(&Kbase[(size_t)sr * 64 + sg], (char*)&Ks[0][0] + o);
  gl_lds16(&VTbase[(size_t)sr * 2048 + sg], (char*)&Vs[0][0] + o);
  gl_lds16(&Kbase[(size_t)(64 + sr) * 64 + sg], (char*)&Ks[1][0] + o);
  gl_lds16(&VTbase[(size_t)sr * 2048 + 64 + sg], (char*)&Vs[1][0] + o);
  __syncthreads();                            // prologue staging visible

  f32x4 acc_o[4];
#pragma unroll
  for (int j = 0; j < 4; ++j) acc_o[j] = ZERO;

  float* arow = attn_out + ((size_t)bh * 2048 + qrow) * 2048;
  u16* Pw = &Ps[w][0];

  for (int it = 0; it < 32; ++it) {
    const int kt = it * 64;
    if (it + 2 < 32) {                         // prefetch distance 2
      const int nb = (it + 2) % 3;
      gl_lds16(&Kbase[(size_t)(kt + 128 + sr) * 64 + sg], (char*)&Ks[nb][0] + o);
      gl_lds16(&VTbase[(size_t)sr * 2048 + kt + 128 + sg], (char*)&Vs[nb][0] + o);
    }
    const u16* Kb = &Ks[it % 3][0];
    const u16* Vb = &Vs[it % 3][0];

    // S^T tile: lane holds S[k=kt+jj*16+lg*4+r][q=qrow]
    f32x4 sacc[4];
#pragma unroll
    for (int jj = 0; jj < 4; ++jj) sacc[jj] = ZERO;
#pragma unroll
    for (int sl = 0; sl < 2; ++sl) {
#pragma unroll
      for (int jj = 0; jj < 4; ++jj) {
        int R = jj * 16 + lr;
        int gs = lg + sl * 4;
        bf16x8 kb = *(const bf16x8*)&Kb[R * 64 + ((gs ^ (R & 7)) << 3)];
        sacc[jj] = __builtin_amdgcn_mfma_f32_16x16x32_bf16(kb, qa[sl], sacc[jj], 0, 0, 0);
      }
    }

    // exp; non-temporal float4 attn store; P -> per-wave LDS (8B x4)
#pragma unroll
    for (int jj = 0; jj < 4; ++jj) {
      f32x4 e;
#pragma unroll
      for (int r = 0; r < 4; ++r)
        e[r] = __expf(fminf(sacc[jj][r] * 0.125f, 30.f));
      f32x4 st = e * linv;
      __builtin_nontemporal_store(st, (f32x4*)&arow[kt + jj * 16 + lg * 4]);
      u32 p01 = cvt_pk_bf16(e[0], e[1]);
      u32 p23 = cvt_pk_bf16(e[2], e[3]);
      *(uint2*)&Pw[lr * 72 + jj * 16 + lg * 4] = make_uint2(p01, p23);
    }
    asm volatile("s_waitcnt lgkmcnt(0)" ::: "memory");
    __builtin_amdgcn_sched_barrier(0);

    // PV: A = P (rows q), B = V (rows d)
    bf16x8 pa[2];
#pragma unroll
    for (int sl = 0; sl < 2; ++sl)
      pa[sl] = *(const bf16x8*)&Pw[lr * 72 + sl * 32 + lg * 8];
#pragma unroll
    for (int jj = 0; jj < 4; ++jj) {
#pragma unroll
      for (int sl = 0; sl < 2; ++sl) {
        int R = jj * 16 + lr;
        int gs = lg + sl * 4;
        bf16x8 vb = *(const bf16x8*)&Vb[R * 64 + ((gs ^ (R & 7)) << 3)];
        acc_o[jj] = __builtin_amdgcn_mfma_f32_16x16x32_bf16(pa[sl], vb, acc_o[jj], 0, 0, 0);
      }
    }

    if (it < 31) {
      // retire exactly the staging for tile it+1 (issued last iter);
      // newer ops left in flight: stores(it-1)[<=4] + stage(it+2)[2] + stores(it)[4]
      __builtin_amdgcn_sched_barrier(0);
      if (it == 30) { asm volatile("s_waitcnt vmcnt(8)" ::: "memory"); }
      else          { asm volatile("s_waitcnt vmcnt(10)" ::: "memory"); }
      __builtin_amdgcn_s_barrier();
      __builtin_amdgcn_sched_barrier(0);
    }
  }

  // epilogue: ctx = O / l (bf16); l for row q=w*16+lg*4+r fetched via shfl
  const int bb = bh >> 4, h = bh & 15;
  float linv2[4];
#pragma unroll
  for (int r = 0; r < 4; ++r)
    linv2[r] = 1.f / __shfl(lacc, lg * 4 + r);
#pragma unroll
  for (int jj = 0; jj < 4; ++jj) {
#pragma unroll
    for (int r = 0; r < 4; ++r) {
      int srow = q0 + w * 16 + lg * 4 + r;
      ctx[((size_t)bb * 2048 + srow) * 1024 + h * 64 + jj * 16 + lr] =
          f2bf(acc_o[jj][r] * linv2[r]);
    }
  }
}

// ---------------- residual + LayerNorm (ctx bf16, residual f32) ----------------
__global__ void __launch_bounds__(256) ln_kernel(
    const u16* __restrict__ ctx, const float* __restrict__ res, float* __restrict__ out)
{
  __shared__ float red[8];
  int row = blockIdx.x;
  int t = threadIdx.x;
  int lane = t & 63, w = t >> 6;
  size_t base = (size_t)row * 1024 + t * 4;
  ushort4 cv = *(const ushort4*)&ctx[base];
  float4 rs = *(const float4*)&res[base];
  float x0 = bf2f(cv.x) + rs.x, x1 = bf2f(cv.y) + rs.y;
  float x2 = bf2f(cv.z) + rs.z, x3 = bf2f(cv.w) + rs.w;
  float s = x0 + x1 + x2 + x3;
  float q = x0 * x0 + x1 * x1 + x2 * x2 + x3 * x3;
#pragma unroll
  for (int off = 1; off < 64; off <<= 1) {
    s += __shfl_xor(s, off);
    q += __shfl_xor(q, off);
  }
  if (lane == 0) { red[w] = s; red[w + 4] = q; }
  __syncthreads();
  s = red[0] + red[1] + red[2] + red[3];
  q = red[4] + red[5] + red[6] + red[7];
  float mu = s * (1.f / 1024.f);
  float var = q * (1.f / 1024.f) - mu * mu;
  float inv = rsqrtf(var + 1e-5f);
  float4 o;
  o.x = (x0 - mu) * inv; o.y = (x1 - mu) * inv; o.z = (x2 - mu) * inv; o.w = (x3 - mu) * inv;
  *(float4*)&out[base] = o;
}

extern "C" void kernel_launch(void* const* d_in, const int* in_sizes, int n_in,
                              void* d_out, int out_size, void* d_ws, size_t ws_size,
                              hipStream_t stream) {
  (void)in_sizes; (void)n_in; (void)out_size; (void)ws_size;
  const float* inQ = (const float*)d_in[0];
  const float* inK = (const float*)d_in[1];
  const float* inV = (const float*)d_in[2];
  const float* wQ  = (const float*)d_in[3];
  const float* wK  = (const float*)d_in[4];
  const float* wV  = (const float*)d_in[5];

  char* ws = (char*)d_ws;
  const size_t NELEM = 4096u * 1024u;
  u16* Qbf  = (u16*)(ws);                        // 8MB  [b,h,s,d] bf16
  u16* Kbf  = (u16*)(ws + (8ull << 20));         // 8MB
  u16* VTbf = (u16*)(ws + (16ull << 20));        // 8MB  [b,h,d,s] bf16
  u16* Xq   = (u16*)(ws + (24ull << 20));
  u16* Xk   = (u16*)(ws + (32ull << 20));
  u16* Xv   = (u16*)(ws + (40ull << 20));
  u16* Wqb  = (u16*)(ws + (48ull << 20));
  u16* Wkb  = (u16*)(ws + (50ull << 20));
  u16* Wvb  = (u16*)(ws + (52ull << 20));
  u16* ctx  = (u16*)(ws + (56ull << 20));        // 8MB bf16 [b,s,1024]

  float* out  = (float*)d_out;
  float* attn = out + NELEM;

  dim3 b256(256);
  cvt3_kernel<<<dim3(4096, 3), b256, 0, stream>>>(inQ, inK, inV, Xq, Xk, Xv, (int)(NELEM / 4));
  cvt3_kernel<<<dim3(1024, 3), b256, 0, stream>>>(wQ, wK, wV, Wqb, Wkb, Wvb, 1048576 / 4);

  proj_gemm<<<dim3(8, 32, 3), b256, 0, stream>>>(Xq, Xk, Xv, Wqb, Wkb, Wvb, Qbf, Kbf, VTbf);

  attn_fused<<<dim3(512), dim3(512), 0, stream>>>(Qbf, Kbf, VTbf, attn, ctx);

  ln_kernel<<<dim3(4096), b256, 0, stream>>>(ctx, inQ, out);
}